// Round 1
// baseline (565.588 us; speedup 1.0000x reference)
//
#include <hip/hip_runtime.h>

#define NN 25000
#define EE 400000
#define FIN 133
#define HCC 512

// ---------------- zero the degree counters (ws is poisoned each call) ------
__global__ __launch_bounds__(256) void k_zero(int* __restrict__ cnt) {
    int i = blockIdx.x * 256 + threadIdx.x;
    if (i < NN) cnt[i] = 0;
}

// ---------------- xl = x@Wl, xr = x@Wr  (f32 tiled GEMM, BM=32 BN=64) ------
__global__ __launch_bounds__(256) void k_gemm(
    const float* __restrict__ x, const float* __restrict__ Wl,
    const float* __restrict__ Wr, float* __restrict__ xl, float* __restrict__ xr)
{
    const float* W  = blockIdx.z ? Wr : Wl;
    float*       out = blockIdx.z ? xr : xl;
    const int row0 = blockIdx.y * 32;
    const int col0 = blockIdx.x * 64;
    __shared__ float As[32][FIN];   // 17 KB
    __shared__ float Bs[FIN][64];   // 34 KB
    const int tid = threadIdx.x;
    for (int idx = tid; idx < 32 * FIN; idx += 256) {
        int r = idx / FIN;
        int k = idx - r * FIN;
        int row = row0 + r;
        As[r][k] = (row < NN) ? x[(size_t)row * FIN + k] : 0.f;
    }
    for (int idx = tid; idx < FIN * 64; idx += 256) {
        int k = idx >> 6, c = idx & 63;
        Bs[k][c] = W[(size_t)k * HCC + col0 + c];
    }
    __syncthreads();
    const int tr = tid >> 4, tc = tid & 15;
    const int r0 = tr * 2, c0 = tc * 4;
    float acc[2][4] = {};
    for (int k = 0; k < FIN; ++k) {
        float a0 = As[r0][k];
        float a1 = As[r0 + 1][k];
        float4 b = *(const float4*)&Bs[k][c0];
        acc[0][0] += a0 * b.x; acc[0][1] += a0 * b.y; acc[0][2] += a0 * b.z; acc[0][3] += a0 * b.w;
        acc[1][0] += a1 * b.x; acc[1][1] += a1 * b.y; acc[1][2] += a1 * b.z; acc[1][3] += a1 * b.w;
    }
    #pragma unroll
    for (int i = 0; i < 2; ++i) {
        int row = row0 + r0 + i;
        if (row < NN) {
            float4 v = make_float4(acc[i][0], acc[i][1], acc[i][2], acc[i][3]);
            *(float4*)&out[(size_t)row * HCC + col0 + c0] = v;
        }
    }
}

// ---------------- in-degree histogram over dst ----------------------------
__global__ __launch_bounds__(256) void k_count(const int* __restrict__ dst,
                                               int* __restrict__ cnt) {
    int e = blockIdx.x * 256 + threadIdx.x;
    if (e < EE) atomicAdd(&cnt[dst[e]], 1);
}

// ---------------- exclusive scan (single block) + dinv --------------------
__global__ __launch_bounds__(256) void k_scan(const int* __restrict__ cnt,
    int* __restrict__ offs, int* __restrict__ cursor, float* __restrict__ dinv)
{
    __shared__ int sdata[256];
    __shared__ int carry_s;
    const int tid = threadIdx.x;
    if (tid == 0) carry_s = 0;
    __syncthreads();
    for (int base = 0; base < NN; base += 256) {
        int i = base + tid;
        int v = (i < NN) ? cnt[i] : 0;
        if (i < NN) dinv[i] = rsqrtf((float)(v + 1));   // deg incl self loop
        sdata[tid] = v;
        __syncthreads();
        for (int off = 1; off < 256; off <<= 1) {
            int t = (tid >= off) ? sdata[tid - off] : 0;
            __syncthreads();
            sdata[tid] += t;
            __syncthreads();
        }
        int incl = sdata[tid];
        int c = carry_s;
        if (i < NN) { int ex = c + incl - v; offs[i] = ex; cursor[i] = ex; }
        __syncthreads();
        if (tid == 255) carry_s = c + incl;
        __syncthreads();
    }
    if (tid == 0) offs[NN] = carry_s;
}

// ---------------- scatter edges into CSR (by dst) -------------------------
__global__ __launch_bounds__(256) void k_scatter(const int* __restrict__ src,
    const int* __restrict__ dst, int* __restrict__ cursor, int* __restrict__ csr)
{
    int e = blockIdx.x * 256 + threadIdx.x;
    if (e < EE) {
        int d = dst[e];
        int pos = atomicAdd(&cursor[d], 1);
        csr[pos] = src[e];
    }
}

// ---------------- GATv2 per-node (one wave per dst) + BN/PReLU/Wg ---------
__global__ __launch_bounds__(256) void k_gat(
    const float* __restrict__ xl, const float* __restrict__ xr,
    const float* __restrict__ att, const float* __restrict__ b1,
    const float* __restrict__ gam, const float* __restrict__ bet,
    const float* __restrict__ mean, const float* __restrict__ var,
    const float* __restrict__ pw, const float* __restrict__ Wg,
    const int* __restrict__ offs, const int* __restrict__ csr,
    float* __restrict__ h2)
{
    const int lane = threadIdx.x & 63;
    const int node = blockIdx.x * 4 + (threadIdx.x >> 6);  // grid = NN/4 exactly
    const int sb = lane * 8;                               // 8 contiguous ch, one head
    float4 xr0 = *(const float4*)&xr[(size_t)node * HCC + sb];
    float4 xr1 = *(const float4*)&xr[(size_t)node * HCC + sb + 4];
    float4 a0 = *(const float4*)&att[sb];
    float4 a1 = *(const float4*)&att[sb + 4];
    float m = -3.0e38f, s = 0.f;
    float acc[8] = {0.f, 0.f, 0.f, 0.f, 0.f, 0.f, 0.f, 0.f};
    const int beg = offs[node], end = offs[node + 1];
    auto lrelu = [](float t) { return t >= 0.f ? t : 0.2f * t; };
    auto process = [&](int srcn) {
        const float* p = &xl[(size_t)srcn * HCC + sb];
        float4 v0 = *(const float4*)p;
        float4 v1 = *(const float4*)(p + 4);
        float ep = lrelu(v0.x + xr0.x) * a0.x + lrelu(v0.y + xr0.y) * a0.y
                 + lrelu(v0.z + xr0.z) * a0.z + lrelu(v0.w + xr0.w) * a0.w
                 + lrelu(v1.x + xr1.x) * a1.x + lrelu(v1.y + xr1.y) * a1.y
                 + lrelu(v1.z + xr1.z) * a1.z + lrelu(v1.w + xr1.w) * a1.w;
        ep += __shfl_xor(ep, 1);
        ep += __shfl_xor(ep, 2);
        ep += __shfl_xor(ep, 4);        // logit for this head, replicated in 8-lane group
        float mn = fmaxf(m, ep);
        float sc = __expf(m - mn);
        float w  = __expf(ep - mn);
        s = s * sc + w;
        float vv[8] = {v0.x, v0.y, v0.z, v0.w, v1.x, v1.y, v1.z, v1.w};
        #pragma unroll
        for (int k = 0; k < 8; ++k) acc[k] = acc[k] * sc + w * vv[k];
        m = mn;
    };
    process(node);                          // self loop
    for (int j = beg; j < end; ++j) process(csr[j]);
    float inv = 1.f / s;
    float p_w = pw[0];
    float dot = 0.f;
    #pragma unroll
    for (int k = 0; k < 8; ++k) {
        int idx = sb + k;
        float v = acc[k] * inv + b1[idx];
        v = (v - mean[idx]) * rsqrtf(var[idx] + 1e-5f) * gam[idx] + bet[idx];
        v = v >= 0.f ? v : p_w * v;
        dot += v * Wg[idx];
    }
    dot += __shfl_xor(dot, 1);
    dot += __shfl_xor(dot, 2);
    dot += __shfl_xor(dot, 4);
    dot += __shfl_xor(dot, 8);
    dot += __shfl_xor(dot, 16);
    dot += __shfl_xor(dot, 32);
    if (lane == 0) h2[node] = dot;
}

// ---------------- GCN: out[n] = dinv[n]*sum(dinv[src]*h2[src]) + bg -------
__global__ __launch_bounds__(256) void k_gcn(
    const float* __restrict__ h2, const float* __restrict__ dinv,
    const int* __restrict__ offs, const int* __restrict__ csr,
    const float* __restrict__ bg, float* __restrict__ out)
{
    int n = blockIdx.x * 256 + threadIdx.x;
    if (n >= NN) return;
    float dn = dinv[n];
    float s = dn * h2[n];                   // self loop
    int e0 = offs[n], e1 = offs[n + 1];
    for (int j = e0; j < e1; ++j) {
        int src = csr[j];
        s += dinv[src] * h2[src];
    }
    out[n] = dn * s + bg[0];
}

extern "C" void kernel_launch(void* const* d_in, const int* in_sizes, int n_in,
                              void* d_out, int out_size, void* d_ws, size_t ws_size,
                              hipStream_t stream)
{
    const float* x    = (const float*)d_in[0];
    const int*   ei   = (const int*)d_in[1];
    const float* Wl   = (const float*)d_in[2];
    const float* Wr   = (const float*)d_in[3];
    const float* att  = (const float*)d_in[4];
    const float* b1   = (const float*)d_in[5];
    const float* gam  = (const float*)d_in[6];
    const float* bet  = (const float*)d_in[7];
    const float* mean = (const float*)d_in[8];
    const float* var  = (const float*)d_in[9];
    const float* pw   = (const float*)d_in[10];
    const float* Wg   = (const float*)d_in[11];
    const float* bg   = (const float*)d_in[12];
    float* out = (float*)d_out;

    float* xl   = (float*)d_ws;             // 51.2 MB
    float* xr   = xl + (size_t)NN * HCC;    // 51.2 MB
    float* h2   = xr + (size_t)NN * HCC;    // 100 KB
    float* dinv = h2 + NN;                  // 100 KB
    int*   cnt  = (int*)(dinv + NN);        // 100 KB
    int*   offs = cnt + NN;                 // 100 KB
    int*   cursor = offs + NN + 1;          // 100 KB
    int*   csr  = cursor + NN;              // 1.6 MB

    const int* srcp = ei;
    const int* dstp = ei + EE;

    k_zero<<<(NN + 255) / 256, 256, 0, stream>>>(cnt);
    dim3 gg(HCC / 64, (NN + 31) / 32, 2);
    k_gemm<<<gg, 256, 0, stream>>>(x, Wl, Wr, xl, xr);
    k_count<<<(EE + 255) / 256, 256, 0, stream>>>(dstp, cnt);
    k_scan<<<1, 256, 0, stream>>>(cnt, offs, cursor, dinv);
    k_scatter<<<(EE + 255) / 256, 256, 0, stream>>>(srcp, dstp, cursor, csr);
    k_gat<<<NN / 4, 256, 0, stream>>>(xl, xr, att, b1, gam, bet, mean, var, pw, Wg,
                                      offs, csr, h2);
    k_gcn<<<(NN + 255) / 256, 256, 0, stream>>>(h2, dinv, offs, csr, bg, out);
}